// Round 13
// baseline (280.633 us; speedup 1.0000x reference)
//
#include <hip/hip_runtime.h>
#include <stdint.h>

#define T_LEN 4096
#define PAD   128
#define HROWS (T_LEN + 2*PAD)   // 4352 rows (zero pad 128 each side)
#define NCH   256
#define M2    512
#define BG    4
#define NL    8

using f4  = __attribute__((ext_vector_type(4))) float;
using bh8 = __attribute__((ext_vector_type(8))) short;
using s4v = __attribute__((ext_vector_type(4))) short;
using u4  = __attribute__((ext_vector_type(4))) unsigned int;

static __device__ __forceinline__ short f2b(float f){
  unsigned u = __builtin_bit_cast(unsigned, f);
  unsigned r = (u + 0x7FFFu + ((u >> 16) & 1u)) >> 16;
  return (short)r;
}
static __device__ __forceinline__ float b2f(short s){
  unsigned u = ((unsigned)(unsigned short)s) << 16;
  return __builtin_bit_cast(float, u);
}

#define MFMA(a,b,c) __builtin_amdgcn_mfma_f32_16x16x32_bf16((a),(b),(c),0,0,0)

// Per-wave row ownership (8 waves): wave w owns tanh rows [w*32, w*32+32)
// (f=0,1) and sigma rows [256+w*32, 256+w*32+32) (f=2,3).
// W1n[l][tap][w(8)][kk(8)][f(4)][lane(64)][8]
// Wcn[l][w(8)][kk(4; K pad 80->128)][f(4)][lane][8]
// W2n[l][w(8)][kk(8)][f(2; res rows w*32+f*16)][lane][8]
// Es[l][kk(8)][lane][8] (M=16)

// ================= fused prep: all preprocessing in ONE launch =================
#define PAD_BLK0 1024
#define E_BLK0   1280
#define ST_BLK0  1408
#define CB_BLK0  1536
#define H0_BLK0  1600
#define ALL_BLKS 1856

__global__ __launch_bounds__(256) void prep_all(
    const float* __restrict__ audio, const float* __restrict__ spect,
    const int* __restrict__ pos, const float* __restrict__ start_w,
    const float* __restrict__ start_b, const float* __restrict__ cond_w,
    const float* __restrict__ cond_b, const float* __restrict__ pos_emb_w,
    const float* __restrict__ pos_lin_w, const float* __restrict__ pos_lin_b,
    const float* __restrict__ in_w, const float* __restrict__ in_b,
    const float* __restrict__ rs_w, const float* __restrict__ rs_b,
    const float* __restrict__ rs_last_w, const float* __restrict__ rs_last_b,
    const float* __restrict__ end_w, const float* __restrict__ end_b,
    short* __restrict__ W1, short* __restrict__ W2, short* __restrict__ Wcn,
    float* __restrict__ rsb8, short* __restrict__ hA, short* __restrict__ hB,
    short* __restrict__ Es, float* __restrict__ ebl, short* __restrict__ spectT,
    float* __restrict__ cb){
  __shared__ float smem[4224];   // 16.5 KB, shared by variants
  const int bid = blockIdx.x, tid = threadIdx.x;

  if (bid < PAD_BLK0){
    // ---- weights -> bf16 fragment-ordered, vectorized 8-wide groups ----
    const int G1 = NL*3*8*8*4*64;   // 393,216 bh8 groups (W1n)
    const int G2 = NL*8*8*2*64;     // 65,536  groups (W2n)
    const int G4 = NL*8*4*4*64;     // 65,536  groups (Wcn)
    const int n3 = NL*M2;           // 4,096   scalars (rsb8)
    for (int q = bid*256 + tid; q < G1+G2+G4+n3; q += 1024*256){
      if (q < G1){
        int lane = q & 63, f = (q >> 6) & 3, kk = (q >> 8) & 7, w = (q >> 11) & 7;
        int lt = q >> 14;               // l*3 + tap
        int tap = lt % 3, l = lt / 3;
        int o = (f < 2) ? (w*32 + f*16 + (lane & 15)) : (256 + w*32 + (f-2)*16 + (lane & 15));
        int c0 = kk*32 + (lane >> 4)*8;
        const float* src = in_w + (((size_t)(l*M2 + o)*NCH + c0)*3) + tap;
        bh8 pk;
        #pragma unroll
        for (int j = 0; j < 8; ++j) pk[j] = f2b(src[j*3]);
        *(bh8*)(W1 + (size_t)q*8) = pk;
      } else if (q < G1+G2){
        int p = q - G1;
        int lane = p & 63, f = (p >> 6) & 1, kk = (p >> 7) & 7, w = (p >> 10) & 7;
        int l = p >> 13;
        int o = w*32 + f*16 + (lane & 15);
        int c0 = kk*32 + (lane >> 4)*8;
        bh8 pk;
        if (l < 7){
          const f4* s = (const f4*)(rs_w + ((size_t)(l*M2 + o))*NCH + c0);
          f4 a = s[0], bvv = s[1];
          #pragma unroll
          for (int j = 0; j < 4; ++j){ pk[j] = f2b(a[j]); pk[4+j] = f2b(bvv[j]); }
        } else {
          #pragma unroll
          for (int j = 0; j < 8; ++j) pk[j] = 0;
        }
        *(bh8*)(W2 + (size_t)p*8) = pk;
      } else if (q < G1+G2+G4){
        int p = q - G1 - G2;
        int lane = p & 63, f = (p >> 6) & 3, kk = (p >> 8) & 3, w = (p >> 10) & 7;
        int l = p >> 13;
        int o = (f < 2) ? (w*32 + f*16 + (lane & 15)) : (256 + w*32 + (f-2)*16 + (lane & 15));
        int k0 = kk*32 + (lane >> 4)*8;
        bh8 pk;
        if (k0 < 80){
          const f4* s = (const f4*)(cond_w + (size_t)(l*M2 + o)*80 + k0);
          f4 a = s[0], bvv = s[1];
          #pragma unroll
          for (int j = 0; j < 4; ++j){ pk[j] = f2b(a[j]); pk[4+j] = f2b(bvv[j]); }
        } else {
          #pragma unroll
          for (int j = 0; j < 8; ++j) pk[j] = 0;
        }
        *(bh8*)(Wcn + (size_t)p*8) = pk;
      } else {
        int k = q - G1 - G2 - G4;
        int o = k & 511, l = k >> 9;
        rsb8[k] = (l < 7) ? rs_b[l*M2 + o] : 0.f;
      }
    }
  } else if (bid < E_BLK0){
    // ---- zero pad rows of hA/hB ----
    int i = (bid - PAD_BLK0)*256 + tid;              // 0..65535
    short* h = (i < 32768) ? hA : hB;
    int j = (i & 32767) << 3;
    int b = j >> 16;
    int r = j & 65535;
    int row = r >> 8, c = r & 255;
    int grow = (row < PAD) ? row : (T_LEN + PAD + (row - PAD));
    *(u4*)(h + ((size_t)b*HROWS + grow)*NCH + c) = (u4){0,0,0,0};
  } else if (bid < ST_BLK0){
    // ---- E_l = end_w @ W2hi_l + ebl ----
    float* ew_s = smem; float* red = smem + 256;
    int e = bid - E_BLK0;
    const int l = e >> 4, o = e & 15;
    const int c = tid;
    ew_s[c] = end_w[o*256 + c];
    __syncthreads();
    const float* Wsrc = (l < 7) ? (rs_w + ((size_t)(l*M2 + NCH))*NCH) : rs_last_w;
    float acc = 0.f;
    #pragma unroll 8
    for (int cp = 0; cp < 256; ++cp)
      acc += ew_s[cp] * Wsrc[(size_t)cp*NCH + c];
    int kk = c >> 5, g = (c >> 3) & 3, j = c & 7;
    Es[(((size_t)l*8 + kk)*64 + g*16 + o)*8 + j] = f2b(acc);
    float bv = (l < 7) ? rs_b[l*M2 + NCH + c] : rs_last_b[c];
    red[c] = ew_s[c] * bv;
    __syncthreads();
    for (int s = 128; s > 0; s >>= 1){
      if (c < s) red[c] += red[c + s];
      __syncthreads();
    }
    if (c == 0) ebl[l*16 + o] = red[0] + ((l == 0) ? end_b[o] : 0.f);
  } else if (bid < CB_BLK0){
    // ---- spectT transpose (padded 80->128) ----
    float (*tile)[65] = (float(*)[65])smem;
    int e = bid - ST_BLK0;
    int t0 = (e & 63)*64, k0 = (e >> 6)*64;
    for (int i = tid; i < 64*64; i += 256){
      int kr = i >> 6, tt = i & 63;
      int k = k0 + kr;
      tile[kr][tt] = (k < 80) ? spect[(size_t)k*T_LEN + t0 + tt] : 0.f;
    }
    __syncthreads();
    for (int i = tid; i < 64*64; i += 256){
      int r = i >> 6, kk = i & 63;
      spectT[(size_t)(t0 + r)*128 + k0 + kk] = f2b(tile[kk][r]);
    }
  } else if (bid < H0_BLK0){
    // ---- cb[b][ch] = in_b + pos_lin_b + cond_b + pc ----
    int e = bid - CB_BLK0;
    int b = e >> 4;
    int ch = (e & 15)*256 + tid;
    int p = pos[b];
    float acc = pos_lin_b[ch] + in_b[ch] + cond_b[ch];
    for (int k = 0; k < 128; ++k){
      float ev = pos_emb_w[p*128 + k];
      ev = ev > 0.f ? ev : 0.f;
      acc += ev * pos_lin_w[ch*128 + k];
    }
    cb[b*4096 + ch] = acc;
  } else {
    // ---- h0 ----
    float* sw = smem; float* sb = smem + 2048;
    int e = bid - H0_BLK0;
    int b = e >> 6, t0 = (e & 63)*64;
    for (int i = tid; i < NCH*8; i += 256) sw[i] = start_w[i];
    for (int i = tid; i < NCH;   i += 256) sb[i] = start_b[i];
    __syncthreads();
    int t = t0 + (tid & 63);
    int cg = tid >> 6;
    float av[8];
    #pragma unroll
    for (int ic = 0; ic < 8; ++ic) av[ic] = audio[((size_t)(b*8 + ic))*T_LEN + t];
    short* dst = hA + ((size_t)b*HROWS + PAD + t)*NCH;
    for (int c = cg*64; c < cg*64 + 64; ++c){
      float acc = sb[c];
      #pragma unroll
      for (int ic = 0; ic < 8; ++ic) acc += sw[c*8 + ic]*av[ic];
      dst[c] = f2b(acc);
    }
  }
}

// ---------------- fused WaveNet layer (T14 async-stage: cond steps hide halo latency) ----------------
// grid (64 t-tiles, 4 batch), 512 threads. 1 block/CU (128 KB LDS).
// flags: bit0 = first layer (init yacc), bit1 = last layer (skip res/h path)
template<int DIL>
__global__ __launch_bounds__(512, 2) void wn_layer(
    const short* __restrict__ hSrc, short* __restrict__ hDst,
    const short* __restrict__ W1l, const short* __restrict__ W2l,
    const short* __restrict__ Wcl, const short* __restrict__ Esl,
    const short* __restrict__ spectTp,
    const float* __restrict__ cb_l, const float* __restrict__ rsb_l,
    const float* __restrict__ ebl_l, float* __restrict__ yacc,
    int flags){

  constexpr int tbR   = (DIL <= 64) ? DIL : 64;        // per-tap row stride
  constexpr int WROWS = (DIL <= 64) ? (64 + 2*DIL) : 192;

  __shared__ short Ht[WROWS*NCH]; // <=96 KB halo window, XOR-swizzled
  __shared__ short xb[64*NCH];    // 32 KB acts

  const int tid  = threadIdx.x;
  const int w    = tid >> 6, lane = tid & 63;
  const int l15  = lane & 15, g = lane >> 4;
  // bijective XCD-chunked swizzle (256 blocks, 8 XCDs, 32-chunk)
  const int lin  = blockIdx.x + (blockIdx.y << 6);
  const int nl2  = ((lin & 7) << 5) + (lin >> 3);
  const int tile = nl2 & 63, b = nl2 >> 6;
  const int sw8  = (l15 & 7) << 3;   // swizzle for rows with base%8==0 (xb)
  const bool first = flags & 1, last = flags & 2;

  f4 acc[4][4];
  #pragma unroll
  for (int f = 0; f < 4; ++f)
    #pragma unroll
    for (int nf = 0; nf < 4; ++nf) acc[f][nf] = (f4){0.f,0.f,0.f,0.f};

  bh8 Ap[3][4], Bp[3][4];

#define LAc(S, BUF) do{ const short* _p = Wcl + w*8192 + (S)*2048 + lane*8; \
    Ap[BUF][0]=*(const bh8*)(_p);      Ap[BUF][1]=*(const bh8*)(_p+512); \
    Ap[BUF][2]=*(const bh8*)(_p+1024); Ap[BUF][3]=*(const bh8*)(_p+1536); }while(0)
#define LBG(S, BUF) do{ const short* _sp = spectTp + (size_t)(tile*64)*128 + (S)*32 + g*8; \
    Bp[BUF][0]=*(const bh8*)(_sp + ( 0+l15)*128); \
    Bp[BUF][1]=*(const bh8*)(_sp + (16+l15)*128); \
    Bp[BUF][2]=*(const bh8*)(_sp + (32+l15)*128); \
    Bp[BUF][3]=*(const bh8*)(_sp + (48+l15)*128); }while(0)
#define LA1(S, BUF) do{ const int _tap=(S)>>3, _kk=(S)&7; \
    const short* _p = W1l + _tap*131072 + w*16384 + _kk*2048 + lane*8; \
    Ap[BUF][0]=*(const bh8*)(_p);      Ap[BUF][1]=*(const bh8*)(_p+512); \
    Ap[BUF][2]=*(const bh8*)(_p+1024); Ap[BUF][3]=*(const bh8*)(_p+1536); }while(0)
#define LB1(S, BUF) do{ const int _tap=(S)>>3, _kk=(S)&7; \
    const int _tb=_tap*tbR; const int _sw=(((_tb+l15)&7)<<3); \
    const short* _hb = Ht + (_tb+l15)*NCH + ((_kk*32+g*8)^_sw); \
    Bp[BUF][0]=*(const bh8*)(_hb); \
    Bp[BUF][1]=*(const bh8*)(_hb + 16*NCH); \
    Bp[BUF][2]=*(const bh8*)(_hb + 32*NCH); \
    Bp[BUF][3]=*(const bh8*)(_hb + 48*NCH); }while(0)
#define LA2(S, BUF) do{ \
    const short* _p = W2l + w*8192 + (S)*1024 + lane*8; \
    Ap[BUF][0]=*(const bh8*)(_p);      Ap[BUF][1]=*(const bh8*)(_p+512); }while(0)
#define LB2(S, BUF) do{ const int _c=((S)*32+g*8)^sw8; \
    Bp[BUF][0]=*(const bh8*)(xb + ( 0+l15)*NCH + _c); \
    Bp[BUF][1]=*(const bh8*)(xb + (16+l15)*NCH + _c); \
    Bp[BUF][2]=*(const bh8*)(xb + (32+l15)*NCH + _c); \
    Bp[BUF][3]=*(const bh8*)(xb + (48+l15)*NCH + _c); }while(0)

  // ---- cond A prefetch + halo load ISSUE (T14: loads in flight during cond) ----
  LAc(0, 0); LAc(1, 1);

  constexpr int NCHUNK = WROWS*32;            // u4 chunks
  constexpr int KITER  = (NCHUNK + 511)/512;
  u4 hv[KITER];
  #pragma unroll
  for (int k = 0; k < KITER; ++k){
    int i = tid + k*512;
    if (NCHUNK % 512 == 0 || i < NCHUNK){
      int r = i >> 5, c16 = (i & 31) << 3;
      int grow = (DIL <= 64) ? (tile*64 - DIL + r)
                             : (tile*64 + ((r >> 6) - 1)*128 + (r & 63));
      hv[k] = *(const u4*)(hSrc + ((size_t)(b*HROWS + PAD + grow))*NCH + c16);
    }
  }

  LBG(0, 0); LBG(1, 1);

  // ---- 3 cond K-steps (K=96), B from global spectT — no LDS dependency ----
  {
    LAc(2, 2); LBG(2, 2);
    #pragma unroll
    for (int f = 0; f < 4; ++f)
      #pragma unroll
      for (int nf = 0; nf < 4; ++nf)
        acc[f][nf] = MFMA(Ap[0][f], Bp[0][nf], acc[f][nf]);
  }
  {
    LA1(0, 0);       // conv A step0 prefetch
    #pragma unroll
    for (int f = 0; f < 4; ++f)
      #pragma unroll
      for (int nf = 0; nf < 4; ++nf)
        acc[f][nf] = MFMA(Ap[1][f], Bp[1][nf], acc[f][nf]);
  }
  {
    LA1(1, 1);       // conv A step1 prefetch
    #pragma unroll
    for (int f = 0; f < 4; ++f)
      #pragma unroll
      for (int nf = 0; nf < 4; ++nf)
        acc[f][nf] = MFMA(Ap[2][f], Bp[2][nf], acc[f][nf]);
  }

  // ---- halo writes (loads should have landed under cond compute) ----
  #pragma unroll
  for (int k = 0; k < KITER; ++k){
    int i = tid + k*512;
    if (NCHUNK % 512 == 0 || i < NCHUNK){
      int r = i >> 5, c16 = (i & 31) << 3;
      *(u4*)(Ht + r*NCH + (c16 ^ ((r & 7) << 3))) = hv[k];
    }
  }
  __syncthreads();

  // ---- 24 conv K-steps; depth-2, 3-buffer rotation ----
  LB1(0, 0);
  LB1(1, 1);
  #pragma unroll
  for (int s = 0; s < 24; ++s){
    const int cur = s % 3, pf = (s+2) % 3;
    if (s < 22){ LA1(s+2, pf); LB1(s+2, pf); }
    #pragma unroll
    for (int f = 0; f < 4; ++f)
      #pragma unroll
      for (int nf = 0; nf < 4; ++nf)
        acc[f][nf] = MFMA(Ap[cur][f], Bp[cur][nf], acc[f][nf]);
  }

  float bias[4][4];
  #pragma unroll
  for (int f = 0; f < 4; ++f){
    int ch = ((f < 2) ? (w*32 + f*16) : (256 + w*32 + (f-2)*16)) + 4*g;
    f4 t = *(const f4*)(cb_l + b*4096 + ch);
    #pragma unroll
    for (int j = 0; j < 4; ++j) bias[f][j] = t[j];
  }
  float rbv[2][4];
  #pragma unroll
  for (int f = 0; f < 2; ++f){
    f4 t = *(const f4*)(rsb_l + w*32 + f*16 + 4*g);
    #pragma unroll
    for (int j = 0; j < 4; ++j) rbv[f][j] = t[j];
  }

  // ---- gate: fully in-register (wave owns both tanh and sigma halves) ----
  #pragma unroll
  for (int f = 0; f < 2; ++f){
    #pragma unroll
    for (int nf = 0; nf < 4; ++nf){
      int tl = nf*16 + l15;
      s4v pk;
      #pragma unroll
      for (int j = 0; j < 4; ++j){
        float xl = acc[f][nf][j]   + bias[f][j];
        float xh = acc[f+2][nf][j] + bias[f+2][j];
        xl = fminf(fmaxf(xl, -30.f), 30.f);
        xh = fminf(fmaxf(xh, -30.f), 30.f);
        float e2 = __expf(2.f*xl);
        float th = (e2 - 1.f)/(e2 + 1.f);
        float sg = 1.f/(1.f + __expf(-xh));
        pk[j] = f2b(th * sg);
      }
      *(s4v*)(xb + tl*NCH + ((w*32 + f*16 + 4*g) ^ sw8)) = pk;
    }
  }
  if (!last) LA2(0, 0);     // prefetch phase-2 res weights across the barrier
  __syncthreads();

  // ---- phase 2: res 1x1 (all 8 waves, 32 rows each) + skip-folded y partial ----
  if (!last){
    #pragma unroll
    for (int f = 0; f < 2; ++f)
      #pragma unroll
      for (int nf = 0; nf < 4; ++nf) acc[f][nf] = (f4){0.f,0.f,0.f,0.f};
    LB2(0, 0);
    #pragma unroll
    for (int s = 0; s < 8; ++s){
      const int cur = s & 1, nxt = cur ^ 1;
      if (s < 7){ LA2(s+1, nxt); LB2(s+1, nxt); }
      #pragma unroll
      for (int f = 0; f < 2; ++f)
        #pragma unroll
        for (int nf = 0; nf < 4; ++nf)
          acc[f][nf] = MFMA(Ap[cur][f], Bp[cur][nf], acc[f][nf]);
    }
    constexpr int swcBase = tbR & 7;
    const int swc = (((swcBase + l15) & 7) << 3);   // center-tap row swizzle
    #pragma unroll
    for (int f = 0; f < 2; ++f){
      #pragma unroll
      for (int nf = 0; nf < 4; ++nf){
        int tl = nf*16 + l15;
        int cb0 = w*32 + f*16 + 4*g;
        s4v hold = *(const s4v*)(Ht + (tbR + tl)*NCH + (cb0 ^ swc));  // h_old (center tap)
        s4v pk;
        #pragma unroll
        for (int j = 0; j < 4; ++j)
          pk[j] = f2b(b2f(hold[j]) + acc[f][nf][j] + rbv[f][j]);
        *(s4v*)(hDst + ((size_t)b*HROWS + PAD + tile*64 + tl)*NCH + cb0) = pk;
      }
    }
  }
  // skip path folded through end_w: wave w computes t-quarter (w&3), kk-half (w>>2)
  {
    const int nfq = w & 3, kh = w >> 2;
    f4 ya = (f4){0.f,0.f,0.f,0.f};
    #pragma unroll
    for (int s = 0; s < 4; ++s){
      int kks = kh*4 + s;
      bh8 av = *(const bh8*)(Esl + ((size_t)kks*64 + lane)*8);
      bh8 bv = *(const bh8*)(xb + (nfq*16 + l15)*NCH + ((kks*32 + g*8) ^ sw8));
      ya = MFMA(av, bv, ya);
    }
    float* yp = yacc + (((size_t)(b*T_LEN + tile*64 + nfq*16 + l15))*2 + kh)*16 + g*4;
    f4 prev = first ? (f4){0.f,0.f,0.f,0.f} : *(const f4*)yp;
    f4 o;
    #pragma unroll
    for (int j = 0; j < 4; ++j)
      o[j] = prev[j] + ya[j] + ((kh == 0) ? ebl_l[g*4 + j] : 0.f);
    *(f4*)yp = o;
  }
#undef LAc
#undef LBG
#undef LA1
#undef LB1
#undef LA2
#undef LB2
}

// ---------------- final: y from fp32 yacc 2 slots (sum + transpose) ----------------
__global__ void final_y(const float* __restrict__ yacc, float* __restrict__ y){
  __shared__ float tl[16][65];
  int b = blockIdx.y, t0 = blockIdx.x*64;
  int i = threadIdx.x;
  #pragma unroll
  for (int s = 0; s < 4; ++s){
    int idx = i + s*256;          // 0..1023
    int t = idx >> 4, o = idx & 15;
    size_t base = ((size_t)(b*T_LEN + t0 + t))*32 + o;
    tl[o][t] = yacc[base] + yacc[base + 16];
  }
  __syncthreads();
  #pragma unroll
  for (int s = 0; s < 4; ++s){
    int idx = i + s*256;
    int o = idx >> 6, t = idx & 63;
    float v = tl[o][t];
    float* dst = (o < 8) ? (y + ((size_t)(b*8 + o))*T_LEN)
                         : (y + 131072 + ((size_t)(b*8 + o - 8))*T_LEN);
    dst[t0 + t] = v;
  }
}

extern "C" void kernel_launch(void* const* d_in, const int* in_sizes, int n_in,
                              void* d_out, int out_size, void* d_ws, size_t ws_size,
                              hipStream_t stream){
  const float* audio      = (const float*)d_in[0];
  const float* spect      = (const float*)d_in[1];
  const int*   pos        = (const int*)  d_in[2];
  const float* start_w    = (const float*)d_in[3];
  const float* start_b    = (const float*)d_in[4];
  const float* cond_w     = (const float*)d_in[5];
  const float* cond_b     = (const float*)d_in[6];
  const float* pos_emb_w  = (const float*)d_in[7];
  const float* pos_lin_w  = (const float*)d_in[8];
  const float* pos_lin_b  = (const float*)d_in[9];
  const float* in_w       = (const float*)d_in[10];
  const float* in_b       = (const float*)d_in[11];
  const float* rs_w       = (const float*)d_in[12];
  const float* rs_b       = (const float*)d_in[13];
  const float* rs_last_w  = (const float*)d_in[14];
  const float* rs_last_b  = (const float*)d_in[15];
  const float* end_w      = (const float*)d_in[16];
  const float* end_b      = (const float*)d_in[17];
  float* y = (float*)d_out;

  char* ws = (char*)d_ws;
  size_t off = 0;
  auto alloc = [&](size_t bytes) -> void* {
    void* p = ws + off;
    off += (bytes + 255) & ~(size_t)255;
    return p;
  };
  const size_t hBytes = (size_t)BG*HROWS*NCH*2;     // 8,912,896
  short* hA     = (short*)alloc(hBytes);
  short* hB     = (short*)alloc(hBytes);
  short* W1     = (short*)alloc((size_t)NL*3*8*8*4*512*2);   // 6 MB
  short* W2     = (short*)alloc((size_t)NL*8*8*2*512*2);     // 1 MB
  short* Wcn    = (short*)alloc((size_t)NL*8*4*4*512*2);     // 1 MB
  float* rsb8   = (float*)alloc((size_t)NL*M2*4);
  float* cb     = (float*)alloc((size_t)BG*4096*4);
  short* spectT = (short*)alloc((size_t)4096*128*2);
  short* Es     = (short*)alloc((size_t)NL*8*64*8*2);
  float* ebl    = (float*)alloc((size_t)NL*16*4);
  float* yacc   = (float*)alloc((size_t)BG*T_LEN*2*16*4);    // 2 MB (2 slots)
  if (off > ws_size) return;  // insufficient workspace -> output stays zero (diagnosable)

  prep_all<<<ALL_BLKS, 256, 0, stream>>>(
      audio, spect, pos, start_w, start_b, cond_w, cond_b, pos_emb_w, pos_lin_w,
      pos_lin_b, in_w, in_b, rs_w, rs_b, rs_last_w, rs_last_b, end_w, end_b,
      W1, W2, Wcn, rsb8, hA, hB, Es, ebl, spectT, cb);

  for (int l = 0; l < NL; ++l){
    const short* hS = (l & 1) ? hB : hA;
    short*       hD = (l & 1) ? hA : hB;
    int flags = (l == 0 ? 1 : 0) | (l == NL-1 ? 2 : 0);
    const short* W1p = W1 + (size_t)l*3*131072;
    const short* W2p = W2 + (size_t)l*65536;
    const short* Wcp = Wcn + (size_t)l*65536;
    const short* Esp = Es + (size_t)l*4096;
    const float* cbp = cb + l*M2;
    const float* rbp = rsb8 + l*M2;
    const float* ebp = ebl + l*16;
    dim3 grid(64, BG);
    switch (l){
      case 0: wn_layer<  1><<<grid, 512, 0, stream>>>(hS, hD, W1p, W2p, Wcp, Esp, spectT, cbp, rbp, ebp, yacc, flags); break;
      case 1: wn_layer<  2><<<grid, 512, 0, stream>>>(hS, hD, W1p, W2p, Wcp, Esp, spectT, cbp, rbp, ebp, yacc, flags); break;
      case 2: wn_layer<  4><<<grid, 512, 0, stream>>>(hS, hD, W1p, W2p, Wcp, Esp, spectT, cbp, rbp, ebp, yacc, flags); break;
      case 3: wn_layer<  8><<<grid, 512, 0, stream>>>(hS, hD, W1p, W2p, Wcp, Esp, spectT, cbp, rbp, ebp, yacc, flags); break;
      case 4: wn_layer< 16><<<grid, 512, 0, stream>>>(hS, hD, W1p, W2p, Wcp, Esp, spectT, cbp, rbp, ebp, yacc, flags); break;
      case 5: wn_layer< 32><<<grid, 512, 0, stream>>>(hS, hD, W1p, W2p, Wcp, Esp, spectT, cbp, rbp, ebp, yacc, flags); break;
      case 6: wn_layer< 64><<<grid, 512, 0, stream>>>(hS, hD, W1p, W2p, Wcp, Esp, spectT, cbp, rbp, ebp, yacc, flags); break;
      case 7: wn_layer<128><<<grid, 512, 0, stream>>>(hS, hD, W1p, W2p, Wcp, Esp, spectT, cbp, rbp, ebp, yacc, flags); break;
    }
  }
  final_y<<<dim3(64, BG), 256, 0, stream>>>(yacc, y);
}

// Round 14
// 220.138 us; speedup vs baseline: 1.2748x; 1.2748x over previous
//
#include <hip/hip_runtime.h>
#include <stdint.h>

#define T_LEN 4096
#define PAD   128
#define HROWS (T_LEN + 2*PAD)   // 4352 rows (zero pad 128 each side)
#define NCH   256
#define M2    512
#define BG    4
#define NL    8

using f4  = __attribute__((ext_vector_type(4))) float;
using bh8 = __attribute__((ext_vector_type(8))) short;
using s4v = __attribute__((ext_vector_type(4))) short;
using u4  = __attribute__((ext_vector_type(4))) unsigned int;

static __device__ __forceinline__ short f2b(float f){
  unsigned u = __builtin_bit_cast(unsigned, f);
  unsigned r = (u + 0x7FFFu + ((u >> 16) & 1u)) >> 16;
  return (short)r;
}
static __device__ __forceinline__ float b2f(short s){
  unsigned u = ((unsigned)(unsigned short)s) << 16;
  return __builtin_bit_cast(float, u);
}

#define MFMA(a,b,c) __builtin_amdgcn_mfma_f32_16x16x32_bf16((a),(b),(c),0,0,0)

// Per-wave row ownership (8 waves): wave w owns tanh rows [w*32, w*32+32)
// (f=0,1) and sigma rows [256+w*32, 256+w*32+32) (f=2,3).
// W1n[l][tap][w(8)][kk(8)][f(4)][lane(64)][8]
// Wcn[l][w(8)][kk(4; K pad 80->128)][f(4)][lane][8]
// W2n[l][w(8)][kk(8)][f(2; res rows w*32+f*16)][lane][8]
// Es[l][kk(8)][lane][8] (M=16)

// ================= fused prep: all preprocessing in ONE launch =================
#define PAD_BLK0 1024
#define E_BLK0   1280
#define ST_BLK0  1408
#define CB_BLK0  1536
#define H0_BLK0  1600
#define ALL_BLKS 1856

__global__ __launch_bounds__(256) void prep_all(
    const float* __restrict__ audio, const float* __restrict__ spect,
    const int* __restrict__ pos, const float* __restrict__ start_w,
    const float* __restrict__ start_b, const float* __restrict__ cond_w,
    const float* __restrict__ cond_b, const float* __restrict__ pos_emb_w,
    const float* __restrict__ pos_lin_w, const float* __restrict__ pos_lin_b,
    const float* __restrict__ in_w, const float* __restrict__ in_b,
    const float* __restrict__ rs_w, const float* __restrict__ rs_b,
    const float* __restrict__ rs_last_w, const float* __restrict__ rs_last_b,
    const float* __restrict__ end_w, const float* __restrict__ end_b,
    short* __restrict__ W1, short* __restrict__ W2, short* __restrict__ Wcn,
    float* __restrict__ rsb8, short* __restrict__ hA, short* __restrict__ hB,
    short* __restrict__ Es, float* __restrict__ ebl, short* __restrict__ spectT,
    float* __restrict__ cb){
  __shared__ float smem[4224];   // 16.5 KB, shared by variants
  const int bid = blockIdx.x, tid = threadIdx.x;

  if (bid < PAD_BLK0){
    // ---- weights -> bf16 fragment-ordered, vectorized 8-wide groups ----
    const int G1 = NL*3*8*8*4*64;   // 393,216 bh8 groups (W1n)
    const int G2 = NL*8*8*2*64;     // 65,536  groups (W2n)
    const int G4 = NL*8*4*4*64;     // 65,536  groups (Wcn)
    const int n3 = NL*M2;           // 4,096   scalars (rsb8)
    for (int q = bid*256 + tid; q < G1+G2+G4+n3; q += 1024*256){
      if (q < G1){
        // q bits: lane[0..5] f[6..7] kk[8..10] w[11..13] lt[14..]
        int lane = q & 63, f = (q >> 6) & 3, kk = (q >> 8) & 7, w = (q >> 11) & 7;
        int lt = q >> 14;               // l*3 + tap
        int tap = lt % 3, l = lt / 3;
        int o = (f < 2) ? (w*32 + f*16 + (lane & 15)) : (256 + w*32 + (f-2)*16 + (lane & 15));
        int c0 = kk*32 + (lane >> 4)*8;
        const float* src = in_w + (((size_t)(l*M2 + o)*NCH + c0)*3) + tap;
        bh8 pk;
        #pragma unroll
        for (int j = 0; j < 8; ++j) pk[j] = f2b(src[j*3]);
        *(bh8*)(W1 + (size_t)q*8) = pk;
      } else if (q < G1+G2){
        int p = q - G1;
        // p bits: lane[0..5] f[6] kk[7..9] w[10..12] l[13..]
        int lane = p & 63, f = (p >> 6) & 1, kk = (p >> 7) & 7, w = (p >> 10) & 7;
        int l = p >> 13;
        int o = w*32 + f*16 + (lane & 15);
        int c0 = kk*32 + (lane >> 4)*8;
        bh8 pk;
        if (l < 7){
          const f4* s = (const f4*)(rs_w + ((size_t)(l*M2 + o))*NCH + c0);
          f4 a = s[0], bvv = s[1];
          #pragma unroll
          for (int j = 0; j < 4; ++j){ pk[j] = f2b(a[j]); pk[4+j] = f2b(bvv[j]); }
        } else {
          #pragma unroll
          for (int j = 0; j < 8; ++j) pk[j] = 0;
        }
        *(bh8*)(W2 + (size_t)p*8) = pk;
      } else if (q < G1+G2+G4){
        int p = q - G1 - G2;
        // p bits: lane[0..5] f[6..7] kk[8..9] w[10..12] l[13..]
        int lane = p & 63, f = (p >> 6) & 3, kk = (p >> 8) & 3, w = (p >> 10) & 7;
        int l = p >> 13;
        int o = (f < 2) ? (w*32 + f*16 + (lane & 15)) : (256 + w*32 + (f-2)*16 + (lane & 15));
        int k0 = kk*32 + (lane >> 4)*8;
        bh8 pk;
        if (k0 < 80){
          const f4* s = (const f4*)(cond_w + (size_t)(l*M2 + o)*80 + k0);
          f4 a = s[0], bvv = s[1];
          #pragma unroll
          for (int j = 0; j < 4; ++j){ pk[j] = f2b(a[j]); pk[4+j] = f2b(bvv[j]); }
        } else {
          #pragma unroll
          for (int j = 0; j < 8; ++j) pk[j] = 0;
        }
        *(bh8*)(Wcn + (size_t)p*8) = pk;
      } else {
        int k = q - G1 - G2 - G4;
        int o = k & 511, l = k >> 9;
        rsb8[k] = (l < 7) ? rs_b[l*M2 + o] : 0.f;
      }
    }
  } else if (bid < E_BLK0){
    // ---- zero pad rows of hA/hB ----
    int i = (bid - PAD_BLK0)*256 + tid;              // 0..65535
    short* h = (i < 32768) ? hA : hB;
    int j = (i & 32767) << 3;
    int b = j >> 16;
    int r = j & 65535;
    int row = r >> 8, c = r & 255;
    int grow = (row < PAD) ? row : (T_LEN + PAD + (row - PAD));
    *(u4*)(h + ((size_t)b*HROWS + grow)*NCH + c) = (u4){0,0,0,0};
  } else if (bid < ST_BLK0){
    // ---- E_l = end_w @ W2hi_l + ebl ----
    float* ew_s = smem; float* red = smem + 256;
    int e = bid - E_BLK0;
    const int l = e >> 4, o = e & 15;
    const int c = tid;
    ew_s[c] = end_w[o*256 + c];
    __syncthreads();
    const float* Wsrc = (l < 7) ? (rs_w + ((size_t)(l*M2 + NCH))*NCH) : rs_last_w;
    float acc = 0.f;
    #pragma unroll 8
    for (int cp = 0; cp < 256; ++cp)
      acc += ew_s[cp] * Wsrc[(size_t)cp*NCH + c];
    int kk = c >> 5, g = (c >> 3) & 3, j = c & 7;
    Es[(((size_t)l*8 + kk)*64 + g*16 + o)*8 + j] = f2b(acc);
    float bv = (l < 7) ? rs_b[l*M2 + NCH + c] : rs_last_b[c];
    red[c] = ew_s[c] * bv;
    __syncthreads();
    for (int s = 128; s > 0; s >>= 1){
      if (c < s) red[c] += red[c + s];
      __syncthreads();
    }
    if (c == 0) ebl[l*16 + o] = red[0] + ((l == 0) ? end_b[o] : 0.f);
  } else if (bid < CB_BLK0){
    // ---- spectT transpose (padded 80->128) ----
    float (*tile)[65] = (float(*)[65])smem;
    int e = bid - ST_BLK0;
    int t0 = (e & 63)*64, k0 = (e >> 6)*64;
    for (int i = tid; i < 64*64; i += 256){
      int kr = i >> 6, tt = i & 63;
      int k = k0 + kr;
      tile[kr][tt] = (k < 80) ? spect[(size_t)k*T_LEN + t0 + tt] : 0.f;
    }
    __syncthreads();
    for (int i = tid; i < 64*64; i += 256){
      int r = i >> 6, kk = i & 63;
      spectT[(size_t)(t0 + r)*128 + k0 + kk] = f2b(tile[kk][r]);
    }
  } else if (bid < H0_BLK0){
    // ---- cb[b][ch] = in_b + pos_lin_b + cond_b + pc ----
    int e = bid - CB_BLK0;
    int b = e >> 4;
    int ch = (e & 15)*256 + tid;
    int p = pos[b];
    float acc = pos_lin_b[ch] + in_b[ch] + cond_b[ch];
    for (int k = 0; k < 128; ++k){
      float ev = pos_emb_w[p*128 + k];
      ev = ev > 0.f ? ev : 0.f;
      acc += ev * pos_lin_w[ch*128 + k];
    }
    cb[b*4096 + ch] = acc;
  } else {
    // ---- h0 ----
    float* sw = smem; float* sb = smem + 2048;
    int e = bid - H0_BLK0;
    int b = e >> 6, t0 = (e & 63)*64;
    for (int i = tid; i < NCH*8; i += 256) sw[i] = start_w[i];
    for (int i = tid; i < NCH;   i += 256) sb[i] = start_b[i];
    __syncthreads();
    int t = t0 + (tid & 63);
    int cg = tid >> 6;
    float av[8];
    #pragma unroll
    for (int ic = 0; ic < 8; ++ic) av[ic] = audio[((size_t)(b*8 + ic))*T_LEN + t];
    short* dst = hA + ((size_t)b*HROWS + PAD + t)*NCH;
    for (int c = cg*64; c < cg*64 + 64; ++c){
      float acc = sb[c];
      #pragma unroll
      for (int ic = 0; ic < 8; ++ic) acc += sw[c*8 + ic]*av[ic];
      dst[c] = f2b(acc);
    }
  }
}

// ---------------- fused WaveNet layer (8 waves, contiguous halo window) ----------------
// grid (64 t-tiles, 4 batch), 512 threads. 1 block/CU (144 KB LDS).
// flags: bit0 = first layer (init yacc), bit1 = last layer (skip res/h path)
__global__ __launch_bounds__(512, 2) void wn_layer(
    const short* __restrict__ hSrc, short* __restrict__ hDst,
    const short* __restrict__ W1l, const short* __restrict__ W2l,
    const short* __restrict__ Wcl, const short* __restrict__ Esl,
    const short* __restrict__ spectTp,
    const float* __restrict__ cb_l, const float* __restrict__ rsb_l,
    const float* __restrict__ ebl_l, float* __restrict__ yacc,
    int dil, int flags){

  __shared__ short Ht[192*NCH];    // 96 KB: halo window (<=192 rows), XOR-swizzled
  __shared__ short xb[64*NCH];     // 32 KB: acts[t][c]
  __shared__ short St[64*128];     // 16 KB: spectT tile [t][k], XOR-swizzled

  const int tid  = threadIdx.x;
  const int w    = tid >> 6, lane = tid & 63;
  const int l15  = lane & 15, g = lane >> 4;
  // bijective XCD-chunked swizzle (256 blocks, 8 XCDs, 32-chunk)
  const int lin  = blockIdx.x + (blockIdx.y << 6);
  const int nl2  = ((lin & 7) << 5) + (lin >> 3);
  const int tile = nl2 & 63, b = nl2 >> 6;
  const int sw8  = (l15 & 7) << 3;   // swizzle for rows with base%8==0 (xb, St)
  const bool first = flags & 1, last = flags & 2;
  const int tbR  = (dil <= 64) ? dil : 64;   // per-tap row stride inside window

  f4 acc[4][4];
  #pragma unroll
  for (int f = 0; f < 4; ++f)
    #pragma unroll
    for (int nf = 0; nf < 4; ++nf) acc[f][nf] = (f4){0.f,0.f,0.f,0.f};

  bh8 Ap[3][4], Bp[3][4];

  // steps 0..2: cond (A=Wcn, B=St, K=96); steps 3..26: conv (A=W1n, B=Ht)
#define LAc(S, BUF) do{ const short* _p = Wcl + w*8192 + (S)*2048 + lane*8; \
    Ap[BUF][0]=*(const bh8*)(_p);      Ap[BUF][1]=*(const bh8*)(_p+512); \
    Ap[BUF][2]=*(const bh8*)(_p+1024); Ap[BUF][3]=*(const bh8*)(_p+1536); }while(0)
#define LBc(S, BUF) do{ const int _c=((S)*32+g*8)^sw8; \
    Bp[BUF][0]=*(const bh8*)(St + ( 0+l15)*128 + _c); \
    Bp[BUF][1]=*(const bh8*)(St + (16+l15)*128 + _c); \
    Bp[BUF][2]=*(const bh8*)(St + (32+l15)*128 + _c); \
    Bp[BUF][3]=*(const bh8*)(St + (48+l15)*128 + _c); }while(0)
#define LA1(S, BUF) do{ const int _tap=(S)>>3, _kk=(S)&7; \
    const short* _p = W1l + _tap*131072 + w*16384 + _kk*2048 + lane*8; \
    Ap[BUF][0]=*(const bh8*)(_p);      Ap[BUF][1]=*(const bh8*)(_p+512); \
    Ap[BUF][2]=*(const bh8*)(_p+1024); Ap[BUF][3]=*(const bh8*)(_p+1536); }while(0)
#define LB1(S, BUF) do{ const int _tap=(S)>>3, _kk=(S)&7; \
    const int _tb=_tap*tbR; const int _sw=(((_tb+l15)&7)<<3); \
    const short* _hb = Ht + (_tb+l15)*NCH + ((_kk*32+g*8)^_sw); \
    Bp[BUF][0]=*(const bh8*)(_hb); \
    Bp[BUF][1]=*(const bh8*)(_hb + 16*NCH); \
    Bp[BUF][2]=*(const bh8*)(_hb + 32*NCH); \
    Bp[BUF][3]=*(const bh8*)(_hb + 48*NCH); }while(0)
#define LAX(S, BUF) do{ if((S)<3) LAc((S),BUF); else LA1((S)-3,BUF); }while(0)
#define LBX(S, BUF) do{ if((S)<3) LBc((S),BUF); else LB1((S)-3,BUF); }while(0)
#define LA2(S, BUF) do{ \
    const short* _p = W2l + w*8192 + (S)*1024 + lane*8; \
    Ap[BUF][0]=*(const bh8*)(_p);      Ap[BUF][1]=*(const bh8*)(_p+512); }while(0)
#define LB2(S, BUF) do{ const int _c=((S)*32+g*8)^sw8; \
    Bp[BUF][0]=*(const bh8*)(xb + ( 0+l15)*NCH + _c); \
    Bp[BUF][1]=*(const bh8*)(xb + (16+l15)*NCH + _c); \
    Bp[BUF][2]=*(const bh8*)(xb + (32+l15)*NCH + _c); \
    Bp[BUF][3]=*(const bh8*)(xb + (48+l15)*NCH + _c); }while(0)

  LAX(0, 0);   // issue first (cond) weight fragments before staging

  // ---- stage: halo window (64+2d rows if d<=64, else 3x64) + spectT tile ----
  {
    const int nrows32 = ((dil <= 64) ? (64 + 2*dil) : 192) * 32;
    for (int i = tid; i < nrows32; i += 512){
      int r = i >> 5, c16 = (i & 31) << 3;
      int grow = (dil <= 64) ? (tile*64 - dil + r)
                             : (tile*64 + ((r >> 6) - 1)*128 + (r & 63));
      u4 v = *(const u4*)(hSrc + ((size_t)(b*HROWS + PAD + grow))*NCH + c16);
      *(u4*)(Ht + r*NCH + (c16 ^ ((r & 7) << 3))) = v;
    }
    #pragma unroll
    for (int s = 0; s < 2; ++s){
      int id = tid + s*512;
      int r = id >> 4, c8 = (id & 15) << 3;
      u4 v = *(const u4*)(spectTp + (size_t)(tile*64 + r)*128 + c8);
      *(u4*)(St + r*128 + (c8 ^ ((r & 7) << 3))) = v;
    }
  }
  __syncthreads();

  // ---- phase 1: cond (3) + dilated conv (24) = 27 depth-2 pipelined K-steps ----
  LBX(0, 0);
  LAX(1, 1); LBX(1, 1);
  #pragma unroll
  for (int s = 0; s < 27; ++s){
    const int cur = s % 3, pf = (s+2) % 3;
    if (s < 25){ LAX(s+2, pf); LBX(s+2, pf); }
    #pragma unroll
    for (int f = 0; f < 4; ++f)
      #pragma unroll
      for (int nf = 0; nf < 4; ++nf)
        acc[f][nf] = MFMA(Ap[cur][f], Bp[cur][nf], acc[f][nf]);
  }

  float bias[4][4];
  #pragma unroll
  for (int f = 0; f < 4; ++f){
    int ch = ((f < 2) ? (w*32 + f*16) : (256 + w*32 + (f-2)*16)) + 4*g;
    f4 t = *(const f4*)(cb_l + b*4096 + ch);
    #pragma unroll
    for (int j = 0; j < 4; ++j) bias[f][j] = t[j];
  }
  float rbv[2][4];
  #pragma unroll
  for (int f = 0; f < 2; ++f){
    f4 t = *(const f4*)(rsb_l + w*32 + f*16 + 4*g);
    #pragma unroll
    for (int j = 0; j < 4; ++j) rbv[f][j] = t[j];
  }

  // ---- gate: fully in-register (wave owns both tanh and sigma halves) ----
  #pragma unroll
  for (int f = 0; f < 2; ++f){
    #pragma unroll
    for (int nf = 0; nf < 4; ++nf){
      int tl = nf*16 + l15;
      s4v pk;
      #pragma unroll
      for (int j = 0; j < 4; ++j){
        float xl = acc[f][nf][j]   + bias[f][j];
        float xh = acc[f+2][nf][j] + bias[f+2][j];
        xl = fminf(fmaxf(xl, -30.f), 30.f);
        xh = fminf(fmaxf(xh, -30.f), 30.f);
        float e2 = __expf(2.f*xl);
        float th = (e2 - 1.f)/(e2 + 1.f);
        float sg = 1.f/(1.f + __expf(-xh));
        pk[j] = f2b(th * sg);
      }
      *(s4v*)(xb + tl*NCH + ((w*32 + f*16 + 4*g) ^ sw8)) = pk;
    }
  }
  if (!last) LA2(0, 0);     // prefetch phase-2 res weights across the barrier
  __syncthreads();

  // ---- phase 2: res 1x1 (all 8 waves, 32 rows each) + skip-folded y partial ----
  if (!last){
    #pragma unroll
    for (int f = 0; f < 2; ++f)
      #pragma unroll
      for (int nf = 0; nf < 4; ++nf) acc[f][nf] = (f4){0.f,0.f,0.f,0.f};
    LB2(0, 0);
    #pragma unroll
    for (int s = 0; s < 8; ++s){
      const int cur = s & 1, nxt = cur ^ 1;
      if (s < 7){ LA2(s+1, nxt); LB2(s+1, nxt); }
      #pragma unroll
      for (int f = 0; f < 2; ++f)
        #pragma unroll
        for (int nf = 0; nf < 4; ++nf)
          acc[f][nf] = MFMA(Ap[cur][f], Bp[cur][nf], acc[f][nf]);
    }
    const int swc = (((tbR + l15) & 7) << 3);   // center-tap row swizzle
    #pragma unroll
    for (int f = 0; f < 2; ++f){
      #pragma unroll
      for (int nf = 0; nf < 4; ++nf){
        int tl = nf*16 + l15;
        int cb0 = w*32 + f*16 + 4*g;
        s4v hold = *(const s4v*)(Ht + (tbR + tl)*NCH + (cb0 ^ swc));  // h_old (center tap)
        s4v pk;
        #pragma unroll
        for (int j = 0; j < 4; ++j)
          pk[j] = f2b(b2f(hold[j]) + acc[f][nf][j] + rbv[f][j]);
        *(s4v*)(hDst + ((size_t)b*HROWS + PAD + tile*64 + tl)*NCH + cb0) = pk;
      }
    }
  }
  // skip path folded through end_w: wave w computes t-quarter (w&3), kk-half (w>>2)
  {
    const int nfq = w & 3, kh = w >> 2;
    f4 ya = (f4){0.f,0.f,0.f,0.f};
    #pragma unroll
    for (int s = 0; s < 4; ++s){
      int kks = kh*4 + s;
      bh8 av = *(const bh8*)(Esl + ((size_t)kks*64 + lane)*8);
      bh8 bv = *(const bh8*)(xb + (nfq*16 + l15)*NCH + ((kks*32 + g*8) ^ sw8));
      ya = MFMA(av, bv, ya);
    }
    float* yp = yacc + (((size_t)(b*T_LEN + tile*64 + nfq*16 + l15))*2 + kh)*16 + g*4;
    f4 prev = first ? (f4){0.f,0.f,0.f,0.f} : *(const f4*)yp;
    f4 o;
    #pragma unroll
    for (int j = 0; j < 4; ++j)
      o[j] = prev[j] + ya[j] + ((kh == 0) ? ebl_l[g*4 + j] : 0.f);
    *(f4*)yp = o;
  }
#undef LAc
#undef LBc
#undef LA1
#undef LB1
#undef LAX
#undef LBX
#undef LA2
#undef LB2
}

// ---------------- final: y from fp32 yacc 2 slots (sum + transpose) ----------------
__global__ void final_y(const float* __restrict__ yacc, float* __restrict__ y){
  __shared__ float tl[16][65];
  int b = blockIdx.y, t0 = blockIdx.x*64;
  int i = threadIdx.x;
  #pragma unroll
  for (int s = 0; s < 4; ++s){
    int idx = i + s*256;          // 0..1023
    int t = idx >> 4, o = idx & 15;
    size_t base = ((size_t)(b*T_LEN + t0 + t))*32 + o;
    tl[o][t] = yacc[base] + yacc[base + 16];
  }
  __syncthreads();
  #pragma unroll
  for (int s = 0; s < 4; ++s){
    int idx = i + s*256;
    int o = idx >> 6, t = idx & 63;
    float v = tl[o][t];
    float* dst = (o < 8) ? (y + ((size_t)(b*8 + o))*T_LEN)
                         : (y + 131072 + ((size_t)(b*8 + o - 8))*T_LEN);
    dst[t0 + t] = v;
  }
}

extern "C" void kernel_launch(void* const* d_in, const int* in_sizes, int n_in,
                              void* d_out, int out_size, void* d_ws, size_t ws_size,
                              hipStream_t stream){
  const float* audio      = (const float*)d_in[0];
  const float* spect      = (const float*)d_in[1];
  const int*   pos        = (const int*)  d_in[2];
  const float* start_w    = (const float*)d_in[3];
  const float* start_b    = (const float*)d_in[4];
  const float* cond_w     = (const float*)d_in[5];
  const float* cond_b     = (const float*)d_in[6];
  const float* pos_emb_w  = (const float*)d_in[7];
  const float* pos_lin_w  = (const float*)d_in[8];
  const float* pos_lin_b  = (const float*)d_in[9];
  const float* in_w       = (const float*)d_in[10];
  const float* in_b       = (const float*)d_in[11];
  const float* rs_w       = (const float*)d_in[12];
  const float* rs_b       = (const float*)d_in[13];
  const float* rs_last_w  = (const float*)d_in[14];
  const float* rs_last_b  = (const float*)d_in[15];
  const float* end_w      = (const float*)d_in[16];
  const float* end_b      = (const float*)d_in[17];
  float* y = (float*)d_out;

  char* ws = (char*)d_ws;
  size_t off = 0;
  auto alloc = [&](size_t bytes) -> void* {
    void* p = ws + off;
    off += (bytes + 255) & ~(size_t)255;
    return p;
  };
  const size_t hBytes = (size_t)BG*HROWS*NCH*2;     // 8,912,896
  short* hA     = (short*)alloc(hBytes);
  short* hB     = (short*)alloc(hBytes);
  short* W1     = (short*)alloc((size_t)NL*3*8*8*4*512*2);   // 6 MB
  short* W2     = (short*)alloc((size_t)NL*8*8*2*512*2);     // 1 MB
  short* Wcn    = (short*)alloc((size_t)NL*8*4*4*512*2);     // 1 MB
  float* rsb8   = (float*)alloc((size_t)NL*M2*4);
  float* cb     = (float*)alloc((size_t)BG*4096*4);
  short* spectT = (short*)alloc((size_t)4096*128*2);
  short* Es     = (short*)alloc((size_t)NL*8*64*8*2);
  float* ebl    = (float*)alloc((size_t)NL*16*4);
  float* yacc   = (float*)alloc((size_t)BG*T_LEN*2*16*4);    // 2 MB (2 slots)
  if (off > ws_size) return;  // insufficient workspace -> output stays zero (diagnosable)

  prep_all<<<ALL_BLKS, 256, 0, stream>>>(
      audio, spect, pos, start_w, start_b, cond_w, cond_b, pos_emb_w, pos_lin_w,
      pos_lin_b, in_w, in_b, rs_w, rs_b, rs_last_w, rs_last_b, end_w, end_b,
      W1, W2, Wcn, rsb8, hA, hB, Es, ebl, spectT, cb);

  for (int l = 0; l < NL; ++l){
    const short* hS = (l & 1) ? hB : hA;
    short*       hD = (l & 1) ? hA : hB;
    int flags = (l == 0 ? 1 : 0) | (l == NL-1 ? 2 : 0);
    wn_layer<<<dim3(64, BG), 512, 0, stream>>>(
        hS, hD,
        W1 + (size_t)l*3*131072,
        W2 + (size_t)l*65536,
        Wcn + (size_t)l*65536,
        Es + (size_t)l*4096,
        spectT,
        cb + l*M2,
        rsb8 + l*M2,
        ebl + l*16,
        yacc, 1 << l, flags);
  }
  final_y<<<dim3(64, BG), 256, 0, stream>>>(yacc, y);
}